// Round 1
// baseline (203.428 us; speedup 1.0000x reference)
//
#include <hip/hip_runtime.h>
#include <math.h>

#define IN_DIM   128
#define OUT_DIM  128
#define N_NEIGH  32
#define BATCH    8192
#define B_TILE   16
#define THREADS  512   // 8 waves; grid = 512 blocks = 2 blocks/CU = 16 waves/CU

// Single fused kernel.
// Phase 0 (per block, redundant): fold W_w/W_b/u into v1[128], v2[128], cc.
//   v1[i] = sum_o W_w[o,i]*u[o]; v2[i] = sum_o W_w[o,i]*u[128+o];
//   cc    = sum_o W_b[o]*(u[o]+u[128+o]).
//   W_w is 64 KB and L2/L3-hot across 512 blocks -> ~free, removes the
//   prep-kernel launch + graph dependency that serialized ~8us.
// Phase 1: wave w handles batch rows {2w, 2w+1} (hb = lane>>5) for ALL 33
//   logical rows (32 neighbor rows + sq). Each half-wave reads one 512B row
//   chunk as float4 (1KB per wave-load, perfectly coalesced). r-loop is
//   constant-trip, fully unrolled, 4 rows prefetched ahead (4KB in
//   flight/wave), and 4 rows reduced together with a butterfly multi-reduce
//   (9 shfl per 4 rows instead of 20).
// Phase 2: softmax over n per batch element; transposed 64B-contiguous store.
__global__ __launch_bounds__(THREADS) void gat_fused(const float* __restrict__ ai_sq,
                                                     const float* __restrict__ ai_sn,
                                                     const float* __restrict__ W_w,
                                                     const float* __restrict__ W_b,
                                                     const float* __restrict__ u,
                                                     float* __restrict__ out) {
    const int tid = threadIdx.x;
    const int b0  = blockIdx.x * B_TILE;

    __shared__ __align__(16) float v1s[IN_DIM];
    __shared__ __align__(16) float v2s[IN_DIM];
    __shared__ float r1s[4][IN_DIM];
    __shared__ float r2s[4][IN_DIM];
    __shared__ float ccs;

    // ---- Phase 0: fold weights (coalesced: 128 consecutive threads read one W row)
    {
        const int i = tid & 127;
        const int g = tid >> 7;          // 0..3, wave-uniform
        float a1 = 0.f, a2 = 0.f;
        #pragma unroll 8
        for (int oo = 0; oo < 32; ++oo) {
            const int o = g * 32 + oo;
            const float w = W_w[o * IN_DIM + i];
            a1 = fmaf(w, u[o], a1);
            a2 = fmaf(w, u[OUT_DIM + o], a2);
        }
        r1s[g][i] = a1;
        r2s[g][i] = a2;
        if (tid < 64) {  // wave-0 reduce for the bias scalar
            float s = W_b[tid]      * (u[tid]      + u[OUT_DIM + tid])
                    + W_b[tid + 64] * (u[tid + 64] + u[OUT_DIM + tid + 64]);
            #pragma unroll
            for (int m = 32; m > 0; m >>= 1) s += __shfl_xor(s, m);
            if (tid == 0) ccs = s;
        }
        __syncthreads();
        if (tid < 128) {
            v1s[tid] = r1s[0][tid] + r1s[1][tid] + r1s[2][tid] + r1s[3][tid];
            v2s[tid] = r2s[0][tid] + r2s[1][tid] + r2s[2][tid] + r2s[3][tid];
        }
        __syncthreads();
    }

    const int lane = tid & 63;
    const int w    = tid >> 6;        // 0..7
    const int c    = lane & 31;       // float4 chunk within the 128-float row
    const int hb   = lane >> 5;       // which of the 2 batch rows this wave owns
    const int bl   = 2 * w + hb;      // 0..15
    const float4 v1c = ((const float4*)v1s)[c];
    const float4 v2c = ((const float4*)v2s)[c];
    const float  cc  = ccs;

    __shared__ float t[N_NEIGH + 1][B_TILE + 1];   // +1 pad: conflict-free softmax

    const size_t RS = (size_t)BATCH * (IN_DIM / 4);   // float4 stride between neighbor rows
    const float4* p   = (const float4*)ai_sn + (size_t)(b0 + bl) * (IN_DIM / 4) + c;
    const float4* psq = (const float4*)ai_sq + (size_t)(b0 + bl) * (IN_DIM / 4) + c;

    // ---- Phase 1: stream 32 neighbor rows (4-deep prefetch) + sq row
    float4 q0 = p[0], q1 = p[RS], q2 = p[2 * RS], q3 = p[3 * RS];
    #pragma unroll
    for (int g = 0; g < 8; ++g) {
        float4 n0, n1, n2, n3;
        if (g < 7) {
            const float4* pn = p + (size_t)(4 * g + 4) * RS;
            n0 = pn[0]; n1 = pn[RS]; n2 = pn[2 * RS]; n3 = pn[3 * RS];
        } else {
            n0 = psq[0]; n1 = n0; n2 = n0; n3 = n0;   // prefetch sq row into slot 0
        }
        float d0 = fmaf(q0.x, v2c.x, fmaf(q0.y, v2c.y, fmaf(q0.z, v2c.z, q0.w * v2c.w)));
        float d1 = fmaf(q1.x, v2c.x, fmaf(q1.y, v2c.y, fmaf(q1.z, v2c.z, q1.w * v2c.w)));
        float d2 = fmaf(q2.x, v2c.x, fmaf(q2.y, v2c.y, fmaf(q2.z, v2c.z, q2.w * v2c.w)));
        float d3 = fmaf(q3.x, v2c.x, fmaf(q3.y, v2c.y, fmaf(q3.z, v2c.z, q3.w * v2c.w)));

        // 4-value butterfly multi-reduce over the 32 c-lanes (9 shfl vs 20)
        d0 += __shfl_xor(d0, 16); d1 += __shfl_xor(d1, 16);
        d2 += __shfl_xor(d2, 16); d3 += __shfl_xor(d3, 16);
        float e01 = (lane & 16) ? d1 : d0;
        float e23 = (lane & 16) ? d3 : d2;
        e01 += __shfl_xor(e01, 8);
        e23 += __shfl_xor(e23, 8);
        float z = (lane & 8) ? e23 : e01;
        z += __shfl_xor(z, 4); z += __shfl_xor(z, 2); z += __shfl_xor(z, 1);
        // lane-group -> row: bit3 picks e23 (+2), bit4 picks the odd member (+1)
        if ((lane & 7) == 0) {
            const int rr = 4 * g + ((lane >> 3) & 1) * 2 + ((lane >> 4) & 1);
            t[rr][bl] = z;
        }
        q0 = n0; q1 = n1; q2 = n2; q3 = n3;
    }
    {   // sq row (already prefetched into q0), folded with v1
        float d = fmaf(q0.x, v1c.x, fmaf(q0.y, v1c.y, fmaf(q0.z, v1c.z, q0.w * v1c.w)));
        #pragma unroll
        for (int m = 16; m > 0; m >>= 1) d += __shfl_xor(d, m);
        if (c == 0) t[N_NEIGH][bl] = d;
    }
    __syncthreads();

    // ---- Phase 2: softmax over n (32 values) per batch element
    {
        const int n   = tid & 31;
        const int blb = tid >> 5;     // 0..15
        float mult = t[n][blb] + t[N_NEIGH][blb] + cc;
        float l = mult > 0.f ? mult : 0.01f * mult;
        float mx = l;
        #pragma unroll
        for (int m = 16; m > 0; m >>= 1) mx = fmaxf(mx, __shfl_xor(mx, m));
        float e = expf(l - mx);
        float s = e;
        #pragma unroll
        for (int m = 16; m > 0; m >>= 1) s += __shfl_xor(s, m);
        float res = e / s;
        __syncthreads();
        t[n][blb] = res;
    }
    __syncthreads();

    // transposed store: 64B contiguous per output row per block
    {
        const int nn = tid >> 4;      // 0..31
        const int bb = tid & 15;
        out[(size_t)nn * BATCH + b0 + bb] = t[nn][bb];
    }
}

extern "C" void kernel_launch(void* const* d_in, const int* in_sizes, int n_in,
                              void* d_out, int out_size, void* d_ws, size_t ws_size,
                              hipStream_t stream) {
    const float* ai_sq = (const float*)d_in[0];  // (8192, 128)
    const float* ai_sn = (const float*)d_in[1];  // (32, 8192, 128)
    const float* W_w   = (const float*)d_in[2];  // (128, 128)
    const float* W_b   = (const float*)d_in[3];  // (128,)
    const float* u     = (const float*)d_in[4];  // (256,)
    float* out = (float*)d_out;                  // (32, 8192)

    gat_fused<<<BATCH / B_TILE, THREADS, 0, stream>>>(ai_sq, ai_sn, W_w, W_b, u, out);
}